// Round 1
// baseline (306.809 us; speedup 1.0000x reference)
//
#include <hip/hip_runtime.h>

typedef __bf16 bf16x8 __attribute__((ext_vector_type(8)));
typedef float f32x4 __attribute__((ext_vector_type(4)));
typedef unsigned short u16;
typedef unsigned short u16x8 __attribute__((ext_vector_type(8)));

__device__ __forceinline__ u16 f2b(float f) {
    union { float f; unsigned u; } a; a.f = f;
    unsigned r = a.u + 0x7FFFu + ((a.u >> 16) & 1u);   // RNE
    return (u16)(r >> 16);
}

// ---- weight prep: wt[768][256] bf16 = [Wq|Wkv_K|Wkv_V]^T (c-major), wpt[256][256] bf16 = Wp^T,
// b_all[768] = [bq|bkv]
__global__ void prep_weights(const float* __restrict__ Wq,
                             const float* __restrict__ Wkv,
                             const float* __restrict__ Wp,
                             const float* __restrict__ bq,
                             const float* __restrict__ bkv,
                             u16* __restrict__ wt,
                             u16* __restrict__ wpt,
                             float* __restrict__ b_all)
{
    int idx = blockIdx.x * 256 + threadIdx.x;
    if (idx < 196608) {                       // 768*256
        int c = idx >> 8, k = idx & 255;
        float v = (c < 256) ? Wq[k * 256 + c] : Wkv[k * 512 + (c - 256)];
        wt[idx] = f2b(v);
    } else if (idx < 262144) {                // + 256*256
        int j = idx - 196608;
        int c = j >> 8, k = j & 255;
        wpt[j] = f2b(Wp[k * 256 + c]);
    } else if (idx < 262912) {                // + 768 biases
        int i = idx - 262144;
        b_all[i] = (i < 256) ? bq[i] : bkv[i - 256];
    }
}

// Fully fused windowed attention. 1 block = 1 window (64 tokens x 256 ch), 4 waves, wave w owns
// heads 2w, 2w+1.
// LDS map (64 KiB total, all bf16, XOR-swizzled byte ^= (row&7)<<4):
//   region X [0,32768):  xs[64][256] (stride 512B)  -> later vt chunks [c][n] per wave ([64][64],
//                        stride 128B, at w*8192)    -> later O_lds[64][256] (stride 512B)
//   region Y [32768,65536): per-wave chunk [64][64] (stride 128B, at 32768+w*8192):
//                        Q staging -> K staging -> P staging
__global__ __launch_bounds__(256, 2)
void fused_win_attn(const float* __restrict__ x,
                    const float* __restrict__ mask,
                    const u16* __restrict__ wt,
                    const u16* __restrict__ wpt,
                    const float* __restrict__ b_all,
                    const float* __restrict__ bp,
                    float* __restrict__ out)
{
    __shared__ __align__(16) unsigned char smem[65536];
    const int b   = blockIdx.x;
    const int tid = threadIdx.x;
    const int w   = tid >> 6;
    const int l   = tid & 63;
    const int lr  = l & 15;
    const int lg  = l >> 4;
    const int wdw = b & 255;                    // window index for mask
    const int chunkoff = 32768 + w * 8192;
    const int vtoff    = w * 8192;
    const float scale = 0.17677669529663687f;   // 1/sqrt(32)

    f32x4 zero = {0.f, 0.f, 0.f, 0.f};

    // ---------- Phase 1: stage x -> xs bf16 (swizzled) ----------
    {
        const float* xb = x + (size_t)b * 16384;
#pragma unroll
        for (int it = 0; it < 8; ++it) {
            int g   = it * 256 + tid;           // 8-float group id
            int row = g >> 5;
            int cg  = g & 31;
            const float4 f0 = *(const float4*)(xb + row * 256 + cg * 8);
            const float4 f1 = *(const float4*)(xb + row * 256 + cg * 8 + 4);
            u16x8 t;
            t[0] = f2b(f0.x); t[1] = f2b(f0.y); t[2] = f2b(f0.z); t[3] = f2b(f0.w);
            t[4] = f2b(f1.x); t[5] = f2b(f1.y); t[6] = f2b(f1.z); t[7] = f2b(f1.w);
            int off = row * 512 + ((cg * 16) ^ ((row & 7) << 4));
            *(u16x8*)(smem + off) = t;
        }
    }
    __syncthreads();

    // ---------- Phase 2: QKV projections (per-wave 64 output cols each) ----------
    f32x4 kacc[4][4], qacc[4][4], vacc[4][4];

    // K accumulate
#pragma unroll
    for (int ti = 0; ti < 4; ++ti)
#pragma unroll
        for (int tj = 0; tj < 4; ++tj) kacc[ti][tj] = zero;
#pragma unroll
    for (int ks = 0; ks < 8; ++ks) {
        bf16x8 a[4];
#pragma unroll
        for (int ti = 0; ti < 4; ++ti) {
            int row = ti * 16 + lr;
            a[ti] = *(const bf16x8*)(smem + row * 512 + ((ks * 64 + lg * 16) ^ ((row & 7) << 4)));
        }
#pragma unroll
        for (int tj = 0; tj < 4; ++tj) {
            int c = 256 + w * 64 + tj * 16 + lr;
            bf16x8 bb = *(const bf16x8*)(wt + c * 256 + ks * 32 + lg * 8);
#pragma unroll
            for (int ti = 0; ti < 4; ++ti)
                kacc[ti][tj] = __builtin_amdgcn_mfma_f32_16x16x32_bf16(a[ti], bb, kacc[ti][tj], 0, 0, 0);
        }
    }
    // Q accumulate
#pragma unroll
    for (int ti = 0; ti < 4; ++ti)
#pragma unroll
        for (int tj = 0; tj < 4; ++tj) qacc[ti][tj] = zero;
#pragma unroll
    for (int ks = 0; ks < 8; ++ks) {
        bf16x8 a[4];
#pragma unroll
        for (int ti = 0; ti < 4; ++ti) {
            int row = ti * 16 + lr;
            a[ti] = *(const bf16x8*)(smem + row * 512 + ((ks * 64 + lg * 16) ^ ((row & 7) << 4)));
        }
#pragma unroll
        for (int tj = 0; tj < 4; ++tj) {
            int c = w * 64 + tj * 16 + lr;
            bf16x8 bb = *(const bf16x8*)(wt + c * 256 + ks * 32 + lg * 8);
#pragma unroll
            for (int ti = 0; ti < 4; ++ti)
                qacc[ti][tj] = __builtin_amdgcn_mfma_f32_16x16x32_bf16(a[ti], bb, qacc[ti][tj], 0, 0, 0);
        }
    }

    // stage Q (+bias) into per-wave chunk, extract A-fragments for S
#pragma unroll
    for (int tj = 0; tj < 4; ++tj) {
        float bias = b_all[w * 64 + tj * 16 + lr];
#pragma unroll
        for (int ti = 0; ti < 4; ++ti)
#pragma unroll
            for (int e = 0; e < 4; ++e) {
                int row = ti * 16 + lg * 4 + e;
                *(u16*)(smem + chunkoff + row * 128 + ((((tj * 16 + lr) * 2)) ^ ((row & 7) << 4)))
                    = f2b(qacc[ti][tj][e] + bias);
            }
    }
    bf16x8 aq[2][4];
#pragma unroll
    for (int hl = 0; hl < 2; ++hl)
#pragma unroll
        for (int ti = 0; ti < 4; ++ti) {
            int row = ti * 16 + lr;
            aq[hl][ti] = *(const bf16x8*)(smem + chunkoff + row * 128 +
                                          ((hl * 64 + lg * 16) ^ ((row & 7) << 4)));
        }

    // stage K (+bias) into the same chunk (per-wave private; same-wave DS ops are in-order)
#pragma unroll
    for (int tj = 0; tj < 4; ++tj) {
        float bias = b_all[256 + w * 64 + tj * 16 + lr];
#pragma unroll
        for (int ti = 0; ti < 4; ++ti)
#pragma unroll
            for (int e = 0; e < 4; ++e) {
                int row = ti * 16 + lg * 4 + e;
                *(u16*)(smem + chunkoff + row * 128 + ((((tj * 16 + lr) * 2)) ^ ((row & 7) << 4)))
                    = f2b(kacc[ti][tj][e] + bias);
            }
    }

    // V accumulate (last reader of xs)
#pragma unroll
    for (int ti = 0; ti < 4; ++ti)
#pragma unroll
        for (int tj = 0; tj < 4; ++tj) vacc[ti][tj] = zero;
#pragma unroll
    for (int ks = 0; ks < 8; ++ks) {
        bf16x8 a[4];
#pragma unroll
        for (int ti = 0; ti < 4; ++ti) {
            int row = ti * 16 + lr;
            a[ti] = *(const bf16x8*)(smem + row * 512 + ((ks * 64 + lg * 16) ^ ((row & 7) << 4)));
        }
#pragma unroll
        for (int tj = 0; tj < 4; ++tj) {
            int c = 512 + w * 64 + tj * 16 + lr;
            bf16x8 bb = *(const bf16x8*)(wt + c * 256 + ks * 32 + lg * 8);
#pragma unroll
            for (int ti = 0; ti < 4; ++ti)
                vacc[ti][tj] = __builtin_amdgcn_mfma_f32_16x16x32_bf16(a[ti], bb, vacc[ti][tj], 0, 0, 0);
        }
    }
    __syncthreads();   // xs fully consumed; region X becomes vt chunks

    // stage V transposed: vt[c][n] (+bias)
#pragma unroll
    for (int tj = 0; tj < 4; ++tj) {
        float bias = b_all[512 + w * 64 + tj * 16 + lr];
        int c = tj * 16 + lr;
#pragma unroll
        for (int ti = 0; ti < 4; ++ti)
#pragma unroll
            for (int e = 0; e < 4; ++e) {
                int n = ti * 16 + lg * 4 + e;
                *(u16*)(smem + vtoff + c * 128 + ((n * 2) ^ ((c & 7) << 4)))
                    = f2b(vacc[ti][tj][e] + bias);
            }
    }

    // ---------- Phase 3: attention (per wave: 2 heads) ----------
    f32x4 sH[2][4][4];
#pragma unroll
    for (int hl = 0; hl < 2; ++hl) {
        bf16x8 bk[4];
#pragma unroll
        for (int tj = 0; tj < 4; ++tj) {
            int n = tj * 16 + lr;
            bk[tj] = *(const bf16x8*)(smem + chunkoff + n * 128 +
                                      ((hl * 64 + lg * 16) ^ ((n & 7) << 4)));
        }
#pragma unroll
        for (int ti = 0; ti < 4; ++ti)
#pragma unroll
            for (int tj = 0; tj < 4; ++tj)
                sH[hl][ti][tj] = __builtin_amdgcn_mfma_f32_16x16x32_bf16(aq[hl][ti], bk[tj], zero, 0, 0, 0);
    }

    f32x4 oH[2][4][2];
    const float* mbase = mask + (size_t)wdw * 4096;
#pragma unroll
    for (int hl = 0; hl < 2; ++hl) {
        // scale + mask add
#pragma unroll
        for (int ti = 0; ti < 4; ++ti)
#pragma unroll
            for (int e = 0; e < 4; ++e) {
                int row = ti * 16 + lg * 4 + e;
#pragma unroll
                for (int tj = 0; tj < 4; ++tj)
                    sH[hl][ti][tj][e] = sH[hl][ti][tj][e] * scale + mbase[row * 64 + tj * 16 + lr];
            }
        // softmax (rows spread across 16-lane group; cols = 4 tj tiles x 16 lanes)
        float inv[4][4];
#pragma unroll
        for (int ti = 0; ti < 4; ++ti)
#pragma unroll
            for (int e = 0; e < 4; ++e) {
                float v0 = sH[hl][ti][0][e], v1 = sH[hl][ti][1][e];
                float v2 = sH[hl][ti][2][e], v3 = sH[hl][ti][3][e];
                float m = fmaxf(fmaxf(v0, v1), fmaxf(v2, v3));
#pragma unroll
                for (int d = 1; d < 16; d <<= 1) m = fmaxf(m, __shfl_xor(m, d));
                v0 = __expf(v0 - m); v1 = __expf(v1 - m);
                v2 = __expf(v2 - m); v3 = __expf(v3 - m);
                float s = v0 + v1 + v2 + v3;
#pragma unroll
                for (int d = 1; d < 16; d <<= 1) s += __shfl_xor(s, d);
                inv[ti][e] = 1.0f / s;
                sH[hl][ti][0][e] = v0; sH[hl][ti][1][e] = v1;
                sH[hl][ti][2][e] = v2; sH[hl][ti][3][e] = v3;
            }
        // write unnormalized P into chunk (overwrites K; both heads' S already computed)
#pragma unroll
        for (int ti = 0; ti < 4; ++ti)
#pragma unroll
            for (int e = 0; e < 4; ++e) {
                int row = ti * 16 + lg * 4 + e;
#pragma unroll
                for (int tj = 0; tj < 4; ++tj)
                    *(u16*)(smem + chunkoff + row * 128 + ((((tj * 16 + lr) * 2)) ^ ((row & 7) << 4)))
                        = f2b(sH[hl][ti][tj][e]);
            }
        // PV
#pragma unroll
        for (int ti = 0; ti < 4; ++ti)
#pragma unroll
            for (int tj = 0; tj < 2; ++tj) oH[hl][ti][tj] = zero;
#pragma unroll
        for (int kb = 0; kb < 2; ++kb) {
            bf16x8 ap[4], bv[2];
#pragma unroll
            for (int ti = 0; ti < 4; ++ti) {
                int row = ti * 16 + lr;
                ap[ti] = *(const bf16x8*)(smem + chunkoff + row * 128 +
                                          ((kb * 64 + lg * 16) ^ ((row & 7) << 4)));
            }
#pragma unroll
            for (int tj = 0; tj < 2; ++tj) {
                int c = hl * 32 + tj * 16 + lr;
                bv[tj] = *(const bf16x8*)(smem + vtoff + c * 128 +
                                          ((kb * 64 + lg * 16) ^ ((c & 7) << 4)));
            }
#pragma unroll
            for (int ti = 0; ti < 4; ++ti)
#pragma unroll
                for (int tj = 0; tj < 2; ++tj)
                    oH[hl][ti][tj] = __builtin_amdgcn_mfma_f32_16x16x32_bf16(ap[ti], bv[tj], oH[hl][ti][tj], 0, 0, 0);
        }
        // normalize O rows by 1/sum
#pragma unroll
        for (int ti = 0; ti < 4; ++ti)
#pragma unroll
            for (int tj = 0; tj < 2; ++tj)
#pragma unroll
                for (int e = 0; e < 4; ++e)
                    oH[hl][ti][tj][e] *= inv[ti][e];
    }

    __syncthreads();   // all waves done reading vt chunks; region X becomes O_lds

    // ---------- Phase 4: stage O -> O_lds[64][256] (swizzled) ----------
#pragma unroll
    for (int hl = 0; hl < 2; ++hl)
#pragma unroll
        for (int ti = 0; ti < 4; ++ti)
#pragma unroll
            for (int tj = 0; tj < 2; ++tj)
#pragma unroll
                for (int e = 0; e < 4; ++e) {
                    int row = ti * 16 + lg * 4 + e;
                    int cg  = (2 * w + hl) * 32 + tj * 16 + lr;
                    *(u16*)(smem + row * 512 + ((cg * 2) ^ ((row & 7) << 4)))
                        = f2b(oH[hl][ti][tj][e]);
                }
    __syncthreads();

    // ---------- Phase 5: output projection ----------
    f32x4 pacc[4][4];
#pragma unroll
    for (int ti = 0; ti < 4; ++ti)
#pragma unroll
        for (int tj = 0; tj < 4; ++tj) pacc[ti][tj] = zero;
#pragma unroll
    for (int ks = 0; ks < 8; ++ks) {
        bf16x8 a[4];
#pragma unroll
        for (int ti = 0; ti < 4; ++ti) {
            int row = ti * 16 + lr;
            a[ti] = *(const bf16x8*)(smem + row * 512 + ((ks * 64 + lg * 16) ^ ((row & 7) << 4)));
        }
#pragma unroll
        for (int tj = 0; tj < 4; ++tj) {
            int c = w * 64 + tj * 16 + lr;
            bf16x8 bb = *(const bf16x8*)(wpt + c * 256 + ks * 32 + lg * 8);
#pragma unroll
            for (int ti = 0; ti < 4; ++ti)
                pacc[ti][tj] = __builtin_amdgcn_mfma_f32_16x16x32_bf16(a[ti], bb, pacc[ti][tj], 0, 0, 0);
        }
    }
    // epilogue: + bp, store fp32
    float* ob = out + (size_t)b * 16384;
#pragma unroll
    for (int tj = 0; tj < 4; ++tj) {
        float bias = bp[w * 64 + tj * 16 + lr];
#pragma unroll
        for (int ti = 0; ti < 4; ++ti)
#pragma unroll
            for (int e = 0; e < 4; ++e) {
                int row = ti * 16 + lg * 4 + e;
                ob[row * 256 + w * 64 + tj * 16 + lr] = pacc[ti][tj][e] + bias;
            }
    }
}

extern "C" void kernel_launch(void* const* d_in, const int* in_sizes, int n_in,
                              void* d_out, int out_size, void* d_ws, size_t ws_size,
                              hipStream_t stream) {
    const float* x    = (const float*)d_in[0];
    const float* mask = (const float*)d_in[1];
    const float* Wq   = (const float*)d_in[2];
    const float* bq   = (const float*)d_in[3];
    const float* Wkv  = (const float*)d_in[4];
    const float* bkv  = (const float*)d_in[5];
    const float* Wp   = (const float*)d_in[6];
    const float* bp   = (const float*)d_in[7];
    float* out = (float*)d_out;

    u16*   wt    = (u16*)d_ws;                 // 768*256 bf16
    u16*   wpt   = wt + 768 * 256;             // 256*256 bf16
    float* b_all = (float*)(wpt + 256 * 256);  // 768 f32

    prep_weights<<<1027, 256, 0, stream>>>(Wq, Wkv, Wp, bq, bkv, wt, wpt, b_all);
    fused_win_attn<<<2048, 256, 0, stream>>>(x, mask, wt, wpt, b_all, bp, out);
}